// Round 4
// baseline (247.564 us; speedup 1.0000x reference)
//
#include <hip/hip_runtime.h>
#include <stdint.h>

#define T 4096
#define E 64
#define NWIN 32
#define NBH 32
#define CH 128                 // fused head dim [k|kr]; also chunk key count
#define SMEM_BYTES 49152       // KK 32 KB (Pb overlay) + Vt 16 KB

typedef __attribute__((ext_vector_type(8))) short short8;
typedef __attribute__((ext_vector_type(4))) float f32x4;

__device__ __forceinline__ short f2bf(float x) {
  unsigned u = __float_as_uint(x);
  u += 0x7fffu + ((u >> 16) & 1u);   // round-to-nearest-even
  return (short)(u >> 16);
}

__device__ __forceinline__ void dma16(const void* g, void* l) {
  __builtin_amdgcn_global_load_lds(
      (const __attribute__((address_space(1))) unsigned int*)g,
      (__attribute__((address_space(3))) unsigned int*)l, 16, 0, 0);
}

// ---- kernel 1: fuse k,kr fp32 -> kkb[bh*T][128] bf16 (natural layout) ----
__global__ __launch_bounds__(256)
void fuse_kk(const float* __restrict__ k, const float* __restrict__ kr,
             short* __restrict__ kkb) {
  int gid = blockIdx.x * 256 + threadIdx.x;   // 1,048,576 threads
  int row = gid >> 3;                         // bh*T + t
  int sub = gid & 7;
  int col = sub * 16;                         // fused col 0..112
  const float* src = (col < 64) ? (k + (size_t)row * 64 + col)
                                : (kr + (size_t)row * 64 + (col - 64));
  float4 f0 = ((const float4*)src)[0];
  float4 f1 = ((const float4*)src)[1];
  float4 f2 = ((const float4*)src)[2];
  float4 f3 = ((const float4*)src)[3];
  short8 h0, h1;
  h0[0]=f2bf(f0.x); h0[1]=f2bf(f0.y); h0[2]=f2bf(f0.z); h0[3]=f2bf(f0.w);
  h0[4]=f2bf(f1.x); h0[5]=f2bf(f1.y); h0[6]=f2bf(f1.z); h0[7]=f2bf(f1.w);
  h1[0]=f2bf(f2.x); h1[1]=f2bf(f2.y); h1[2]=f2bf(f2.z); h1[3]=f2bf(f2.w);
  h1[4]=f2bf(f3.x); h1[5]=f2bf(f3.y); h1[6]=f2bf(f3.z); h1[7]=f2bf(f3.w);
  short8* dst = (short8*)(kkb + (size_t)row * CH + col);
  dst[0] = h0; dst[1] = h1;
}

// ---- kernel 2: transpose v fp32 [bh][t][64] -> vtb bf16 [bh][e][t] ----
__global__ __launch_bounds__(256)
void transpose_v(const float* __restrict__ v, short* __restrict__ vtb) {
  __shared__ float tile[64][68];
  const int t0 = blockIdx.x * 64;
  const int bh = blockIdx.y;
  const float* vp = v + ((size_t)bh * T + t0) * E;
  const int r = threadIdx.x >> 4, c = threadIdx.x & 15;
#pragma unroll
  for (int i = 0; i < 4; ++i) {
    float4 f = *(const float4*)(vp + (size_t)(r + 16 * i) * E + c * 4);
    *(float4*)(&tile[r + 16 * i][c * 4]) = f;
  }
  __syncthreads();
  const int e = threadIdx.x >> 2, c2 = threadIdx.x & 3;
  short8 h0, h1;
#pragma unroll
  for (int j = 0; j < 8; ++j) h0[j] = f2bf(tile[c2 * 16 + j][e]);
#pragma unroll
  for (int j = 0; j < 8; ++j) h1[j] = f2bf(tile[c2 * 16 + 8 + j][e]);
  short8* dst = (short8*)(vtb + ((size_t)bh * E + e) * T + t0 + c2 * 16);
  dst[0] = h0; dst[1] = h1;
}

// ---- kernel 3: attention. One block per (window, bh), 8 waves x 16 q-rows.
// LDS: KKs [128 key][128 fused] bf16 swizzled (32 KB; per-wave P tiles overlay
// after B2), Vts [64 e][128 key] bf16 swizzled (16 KB). Swizzle: 16-B block
// cb_l = cb_g ^ (row & 15) -> all b128 fragment reads <=2-way (free).
__global__ __launch_bounds__(512, 4)
void la_attn(const float* __restrict__ qg, const float* __restrict__ qrg,
             const short* __restrict__ kkb, const short* __restrict__ vtb,
             float* __restrict__ outg) {
  extern __shared__ char smem[];
  short* KKs = (short*)smem;                // [128][128]
  short* Vts = (short*)(smem + 32768);      // [64][128]

  const int w = blockIdx.x, bh = blockIdx.y;
  const int tid = threadIdx.x;
  const int wid = tid >> 6, lane = tid & 63;
  const int li = lane & 15, lg = lane >> 4;

  const size_t qbase = (size_t)bh * T * E;
  const int krow0 = w * 128 - 128;
  const int rowb = wid * 16 + lg * 4;

  // ---- Q/Qr -> A-fragments (scale 0.125 folded; exact pow2) ----
  const int qrow = w * 128 + wid * 16 + li;
  const float* qp  = qg  + qbase + (size_t)qrow * E;
  const float* qrp = qrg + qbase + (size_t)qrow * E;
  short8 aF[4];
#pragma unroll
  for (int kt = 0; kt < 4; ++kt) {
    const float* sp = (kt < 2 ? qp : qrp) + (kt & 1) * 32 + lg * 8;
    float4 f0 = *(const float4*)sp;
    float4 f1 = *(const float4*)(sp + 4);
    short8 a;
    a[0]=f2bf(f0.x*0.125f); a[1]=f2bf(f0.y*0.125f); a[2]=f2bf(f0.z*0.125f); a[3]=f2bf(f0.w*0.125f);
    a[4]=f2bf(f1.x*0.125f); a[5]=f2bf(f1.y*0.125f); a[6]=f2bf(f1.z*0.125f); a[7]=f2bf(f1.w*0.125f);
    aF[kt] = a;
  }

  f32x4 O[4] = {{0,0,0,0},{0,0,0,0},{0,0,0,0},{0,0,0,0}};
  float m_run[4] = {-1e30f, -1e30f, -1e30f, -1e30f};
  float l_run[4] = {0.f, 0.f, 0.f, 0.f};

#pragma unroll 1
  for (int c = 0; c < 2; ++c) {
    if (w == 0 && c == 0) continue;   // padding chunk (block-uniform)
    const int kbase = krow0 + c * 128;

    // ---- async DMA stage: 4 KK + 2 Vt instrs per wave ----
    {
      const int rl = lane >> 4;       // row within 4-row group
      const int cbl = lane & 15;      // LDS 16-B block index
      const short* kksrc = kkb + ((size_t)bh * T + kbase) * CH;
#pragma unroll
      for (int ii = 0; ii < 4; ++ii) {
        int r0 = wid * 16 + ii * 4;
        int row = r0 + rl;
        int cbg = cbl ^ (row & 15);
        dma16(kksrc + (size_t)row * CH + cbg * 8, KKs + r0 * CH);
      }
      const short* vsrc = vtb + (size_t)bh * E * T + kbase;
#pragma unroll
      for (int ii = 0; ii < 2; ++ii) {
        int r0 = wid * 8 + ii * 4;
        int e = r0 + rl;
        int cbg = cbl ^ (e & 15);
        dma16(vsrc + (size_t)e * T + cbg * 8, Vts + r0 * CH);
      }
    }
    __syncthreads();   // B1: DMA complete (vmcnt0)

    // ---- S = [Q|Qr]·[K|Kr]^T : 8 col-tiles x 4 k-tiles ----
    // C-layout: lane holds S[row=lg*4+r][col=ct*16+li]
    f32x4 S[8];
#pragma unroll
    for (int ct = 0; ct < 8; ++ct) {
      f32x4 acc = {0.f, 0.f, 0.f, 0.f};
      const short* kb = KKs + (ct * 16 + li) * CH;
#pragma unroll
      for (int kt = 0; kt < 4; ++kt) {
        short8 b = *(const short8*)(kb + ((kt * 4 + lg) ^ li) * 8);
        acc = __builtin_amdgcn_mfma_f32_16x16x32_bf16(aF[kt], b, acc, 0, 0, 0);
      }
      S[ct] = acc;
    }
    __syncthreads();   // B2: all KK reads done -> P-tiles may overlay KKs

    // ---- mask (chunk 1: causal) + online softmax update (registers) ----
    float alpha[4];
#pragma unroll
    for (int r = 0; r < 4; ++r) {
      const int qi = rowb + r;
      float mx = -1e30f;
#pragma unroll
      for (int ct = 0; ct < 8; ++ct) {
        if (c == 1) {
          int jj = ct * 16 + li;
          if (jj > qi) S[ct][r] = -1e30f;
        }
        mx = fmaxf(mx, S[ct][r]);
      }
      mx = fmaxf(mx, __shfl_xor(mx, 1));
      mx = fmaxf(mx, __shfl_xor(mx, 2));
      mx = fmaxf(mx, __shfl_xor(mx, 4));
      mx = fmaxf(mx, __shfl_xor(mx, 8));
      float m_new = fmaxf(m_run[r], mx);
      float al = __expf(m_run[r] - m_new);
      float sm = 0.f;
#pragma unroll
      for (int ct = 0; ct < 8; ++ct) {
        float e = __expf(S[ct][r] - m_new);
        S[ct][r] = e;
        sm += e;
      }
      sm += __shfl_xor(sm, 1);
      sm += __shfl_xor(sm, 2);
      sm += __shfl_xor(sm, 4);
      sm += __shfl_xor(sm, 8);
      l_run[r] = l_run[r] * al + sm;
      m_run[r] = m_new;
      alpha[r] = al;
    }
#pragma unroll
    for (int nt = 0; nt < 4; ++nt)
#pragma unroll
      for (int r = 0; r < 4; ++r)
        O[nt][r] *= alpha[r];

    // ---- P -> own-wave LDS tile (overlay on KKs rows wid*16..+15) ----
    // Swizzled same as KK; read-back is own-wave only -> no barrier needed.
    short* pw = KKs + wid * 16 * CH;
#pragma unroll
    for (int ct = 0; ct < 8; ++ct) {
#pragma unroll
      for (int r = 0; r < 4; ++r) {
        int prow = lg * 4 + r;
        int cbl = ((ct * 2 + (li >> 3)) ^ prow);
        pw[prow * CH + cbl * 8 + (li & 7)] = f2bf(S[ct][r]);
      }
    }

    // ---- O += P·V : 4 k-tiles x 4 n-tiles ----
    short8 aP[4];
#pragma unroll
    for (int kt = 0; kt < 4; ++kt)
      aP[kt] = *(const short8*)(pw + li * CH + ((kt * 4 + lg) ^ li) * 8);
#pragma unroll
    for (int kt = 0; kt < 4; ++kt) {
#pragma unroll
      for (int nt = 0; nt < 4; ++nt) {
        short8 b = *(const short8*)(Vts + (nt * 16 + li) * CH + ((kt * 4 + lg) ^ li) * 8);
        O[nt] = __builtin_amdgcn_mfma_f32_16x16x32_bf16(aP[kt], b, O[nt], 0, 0, 0);
      }
    }
    __syncthreads();   // B3: PV reads done before next chunk's DMA overwrites
  }

  // ---- epilogue: apply 1/l, store fp32 ----
  float* op = outg + qbase + (size_t)(w * 128 + rowb) * E;
#pragma unroll
  for (int r = 0; r < 4; ++r) {
    float linv = 1.f / l_run[r];
#pragma unroll
    for (int nt = 0; nt < 4; ++nt) {
      op[(size_t)r * E + nt * 16 + li] = O[nt][r] * linv;
    }
  }
}

extern "C" void kernel_launch(void* const* d_in, const int* in_sizes, int n_in,
                              void* d_out, int out_size, void* d_ws, size_t ws_size,
                              hipStream_t stream) {
  const float* q  = (const float*)d_in[0];
  const float* k  = (const float*)d_in[1];
  const float* qr = (const float*)d_in[2];
  const float* kr = (const float*)d_in[3];
  const float* v  = (const float*)d_in[4];
  float* out = (float*)d_out;

  short* kkb = (short*)d_ws;                              // 32 MiB
  short* vtb = kkb + (size_t)NBH * T * CH;                // 16 MiB

  fuse_kk<<<4096, 256, 0, stream>>>(k, kr, kkb);
  transpose_v<<<dim3(64, 32), 256, 0, stream>>>(v, vtb);
  la_attn<<<dim3(NWIN, NBH), 512, SMEM_BYTES, stream>>>(q, qr, kkb, vtb, out);
}

// Round 5
// 206.735 us; speedup vs baseline: 1.1975x; 1.1975x over previous
//
#include <hip/hip_runtime.h>
#include <stdint.h>

#define T 4096
#define E 64
#define NBH 32
#define W 4                    // windows per strip (block)
#define LDK 136                // LDS row stride (bf16 elems): 16B-aligned rows, <=2-way banks
#define CHUNK_KK (128*LDK)     // elems
#define CHUNK_VT (64*LDK)
#define BUF_ELEMS (CHUNK_KK + CHUNK_VT)   // 26112 elems = 52224 B
#define SMEM_BYTES (2*BUF_ELEMS*2)        // 104448 B -> 1 block/CU

typedef __attribute__((ext_vector_type(8))) short short8;
typedef __attribute__((ext_vector_type(4))) short short4v;
typedef __attribute__((ext_vector_type(4))) float f32x4;

__device__ __forceinline__ short f2bf(float x) {
  unsigned u = __float_as_uint(x);
  u += 0x7fffu + ((u >> 16) & 1u);   // round-to-nearest-even
  return (short)(u >> 16);
}

// per-thread staging registers for one K/Kr/V chunk (128 keys)
struct ChunkStage { float4 sk[8]; float sv[16]; };

__device__ __forceinline__ void chunk_issue(ChunkStage& st,
    const float* __restrict__ k, const float* __restrict__ kr,
    const float* __restrict__ v, size_t rowbase, int tid, int wid, int lane) {
#pragma unroll
  for (int m = 0; m < 2; ++m) {
    const float* src = m ? kr : k;
#pragma unroll
    for (int it = 0; it < 4; ++it) {
      int idx = it * 512 + tid;
      st.sk[m * 4 + it] = *(const float4*)(src + (rowbase + (idx >> 4)) * E + (idx & 15) * 4);
    }
  }
  const float* vp = v + (rowbase + wid * 16) * E + lane;   // lane = e, 16 t-rows
#pragma unroll
  for (int i = 0; i < 16; ++i) st.sv[i] = vp[(size_t)i * E];
}

__device__ __forceinline__ void chunk_commit(const ChunkStage& st,
    short* __restrict__ KK, short* __restrict__ Vt, int tid, int wid, int lane) {
#pragma unroll
  for (int m = 0; m < 2; ++m) {
#pragma unroll
    for (int it = 0; it < 4; ++it) {
      int idx = it * 512 + tid;
      float4 f = st.sk[m * 4 + it];
      short4v h = { f2bf(f.x), f2bf(f.y), f2bf(f.z), f2bf(f.w) };
      *(short4v*)(KK + (idx >> 4) * LDK + m * 64 + (idx & 15) * 4) = h;
    }
  }
#pragma unroll
  for (int rq = 0; rq < 4; ++rq) {
    short4v h = { f2bf(st.sv[rq*4+0]), f2bf(st.sv[rq*4+1]),
                  f2bf(st.sv[rq*4+2]), f2bf(st.sv[rq*4+3]) };
    *(short4v*)(Vt + lane * LDK + wid * 16 + rq * 4) = h;
  }
}

__device__ __forceinline__ void q_issue(float4* sq,
    const float* __restrict__ q, const float* __restrict__ qr,
    size_t rbase, int w, int wid, int li, int lg) {
  const size_t qrow = rbase + (size_t)w * 128 + wid * 16 + li;
#pragma unroll
  for (int kt = 0; kt < 4; ++kt) {
    const float* sp = (kt < 2 ? q : qr) + qrow * E + (kt & 1) * 32 + lg * 8;
    sq[kt * 2 + 0] = *(const float4*)sp;
    sq[kt * 2 + 1] = *(const float4*)(sp + 4);
  }
}

__device__ __forceinline__ void q_commit(const float4* sq, short8* aF) {
#pragma unroll
  for (int kt = 0; kt < 4; ++kt) {
    float4 f0 = sq[kt * 2], f1 = sq[kt * 2 + 1];
    short8 a;
    a[0]=f2bf(f0.x*0.125f); a[1]=f2bf(f0.y*0.125f); a[2]=f2bf(f0.z*0.125f); a[3]=f2bf(f0.w*0.125f);
    a[4]=f2bf(f1.x*0.125f); a[5]=f2bf(f1.y*0.125f); a[6]=f2bf(f1.z*0.125f); a[7]=f2bf(f1.w*0.125f);
    aF[kt] = a;
  }
}

// One block per (strip of 4 windows, bh). 8 waves x 16 q-rows per window.
// Two ping-pong chunk buffers; chunk c_i (keys of window w0+i) lives in buf[i&1]
// and serves windows i and i+1. Loads for c_{j+1} issued at window-j top (latency
// hidden under compute), committed to LDS after window-j's PV.
__global__ __launch_bounds__(512, 2)
void la_attn(const float* __restrict__ qg, const float* __restrict__ kg,
             const float* __restrict__ qrg, const float* __restrict__ krg,
             const float* __restrict__ vg, float* __restrict__ outg) {
  extern __shared__ short smem[];

  const int strip = blockIdx.x, bh = blockIdx.y;
  const int w0 = strip * W;
  const int tid = threadIdx.x;
  const int wid = tid >> 6, lane = tid & 63;
  const int li = lane & 15, lg = lane >> 4;
  const size_t rbase = (size_t)bh * T;
  const int rowb = wid * 16 + lg * 4;

  short8 aF[4];

  // ---- prologue: stage c_{-1} (if any) + c_0; q window 0 ----
  {
    ChunkStage s1, s0;
    float4 sq[8];
    if (w0 > 0) chunk_issue(s1, kg, krg, vg, rbase + (size_t)(w0 - 1) * 128, tid, wid, lane);
    chunk_issue(s0, kg, krg, vg, rbase + (size_t)w0 * 128, tid, wid, lane);
    q_issue(sq, qg, qrg, rbase, w0, wid, li, lg);
    if (w0 > 0) chunk_commit(s1, smem + BUF_ELEMS, smem + BUF_ELEMS + CHUNK_KK, tid, wid, lane);
    chunk_commit(s0, smem, smem + CHUNK_KK, tid, wid, lane);
    q_commit(sq, aF);
  }
  __syncthreads();

  for (int j = 0; j < W; ++j) {
    short* bufb = smem + ((j + 1) & 1) * BUF_ELEMS;   // backward chunk c_{j-1}
    short* bufc = smem + (j & 1) * BUF_ELEMS;         // current chunk c_j
    short* KKback = bufb;       short* Vtback = bufb + CHUNK_KK;
    short* KKcur  = bufc;       short* Vtcur  = bufc + CHUNK_KK;
    const bool have_next = (j + 1 < W);
    const bool skipback = (w0 == 0 && j == 0);   // block-uniform: padding chunk

    // ---- issue next chunk + next Q loads (in flight during this window) ----
    ChunkStage st;
    float4 sq[8];
    if (have_next) {
      chunk_issue(st, kg, krg, vg, rbase + (size_t)(w0 + j + 1) * 128, tid, wid, lane);
      q_issue(sq, qg, qrg, rbase, w0 + j + 1, wid, li, lg);
    }

    // ---- S = [Q|Qr]·[K|Kr]^T over 256 keys: 16 ct x 4 kt MFMA ----
    // C-layout: lane holds S[row=lg*4+r][col=ct*16+li]
    f32x4 S[16];
    if (!skipback) {
#pragma unroll
      for (int ct = 0; ct < 8; ++ct) {
        f32x4 acc = {0.f, 0.f, 0.f, 0.f};
        const short* kb = KKback + (ct * 16 + li) * LDK + lg * 8;
#pragma unroll
        for (int kt = 0; kt < 4; ++kt)
          acc = __builtin_amdgcn_mfma_f32_16x16x32_bf16(aF[kt], *(const short8*)(kb + kt * 32), acc, 0, 0, 0);
        S[ct] = acc;
      }
    } else {
#pragma unroll
      for (int ct = 0; ct < 8; ++ct) S[ct] = f32x4{-1e30f, -1e30f, -1e30f, -1e30f};
    }
#pragma unroll
    for (int ct = 0; ct < 8; ++ct) {
      f32x4 acc = {0.f, 0.f, 0.f, 0.f};
      const short* kb = KKcur + (ct * 16 + li) * LDK + lg * 8;
#pragma unroll
      for (int kt = 0; kt < 4; ++kt)
        acc = __builtin_amdgcn_mfma_f32_16x16x32_bf16(aF[kt], *(const short8*)(kb + kt * 32), acc, 0, 0, 0);
      S[8 + ct] = acc;
    }

    // ---- mask (current half only: causal) + full-window softmax ----
    float linv[4];
#pragma unroll
    for (int r = 0; r < 4; ++r) {
      const int qi = rowb + r;
#pragma unroll
      for (int ct = 8; ct < 16; ++ct) {
        int jj = (ct - 8) * 16 + li;          // local key pos 0..127
        if (jj > qi) S[ct][r] = -1e30f;
      }
      float mx = -1e30f;
#pragma unroll
      for (int ct = 0; ct < 16; ++ct) mx = fmaxf(mx, S[ct][r]);
      mx = fmaxf(mx, __shfl_xor(mx, 1));
      mx = fmaxf(mx, __shfl_xor(mx, 2));
      mx = fmaxf(mx, __shfl_xor(mx, 4));
      mx = fmaxf(mx, __shfl_xor(mx, 8));
      float sm = 0.f;
#pragma unroll
      for (int ct = 0; ct < 16; ++ct) {
        float e = __expf(S[ct][r] - mx);
        S[ct][r] = e;
        sm += e;
      }
      sm += __shfl_xor(sm, 1);
      sm += __shfl_xor(sm, 2);
      sm += __shfl_xor(sm, 4);
      sm += __shfl_xor(sm, 8);
      linv[r] = 1.f / sm;
    }
    __syncthreads();   // Ba: all S reads of KKback done -> reuse as P scratch

    // ---- PV in two 128-key halves; P via own-wave slice of dead KKback ----
    short* pw = KKback + wid * 16 * LDK;   // [16][LDK] per-wave scratch
    f32x4 O[4] = {{0,0,0,0},{0,0,0,0},{0,0,0,0},{0,0,0,0}};
#pragma unroll
    for (int h = 0; h < 2; ++h) {
      if (h == 0 && skipback) continue;
      const short* Vth = h ? Vtcur : Vtback;
#pragma unroll
      for (int cc = 0; cc < 8; ++cc)
#pragma unroll
        for (int r = 0; r < 4; ++r)
          pw[(lg * 4 + r) * LDK + cc * 16 + li] = f2bf(S[h * 8 + cc][r]);
#pragma unroll
      for (int kt = 0; kt < 4; ++kt) {
        short8 aP = *(const short8*)(pw + li * LDK + kt * 32 + lg * 8);
#pragma unroll
        for (int nt = 0; nt < 4; ++nt) {
          short8 b = *(const short8*)(Vth + (nt * 16 + li) * LDK + kt * 32 + lg * 8);
          O[nt] = __builtin_amdgcn_mfma_f32_16x16x32_bf16(aP, b, O[nt], 0, 0, 0);
        }
      }
    }

    // ---- store this window's output ----
    float* op = outg + (rbase + (size_t)(w0 + j) * 128 + rowb) * E;
#pragma unroll
    for (int r = 0; r < 4; ++r)
#pragma unroll
      for (int nt = 0; nt < 4; ++nt)
        op[(size_t)r * E + nt * 16 + li] = O[nt][r] * linv[r];

    __syncthreads();   // Bb: PV reads of P/Vtback done

    // ---- commit next chunk into the retired backward buffer ----
    if (have_next) {
      chunk_commit(st, KKback, Vtback, tid, wid, lane);
      q_commit(sq, aF);
    }
    __syncthreads();   // Bc: staged data visible for next window
  }
}

extern "C" void kernel_launch(void* const* d_in, const int* in_sizes, int n_in,
                              void* d_out, int out_size, void* d_ws, size_t ws_size,
                              hipStream_t stream) {
  const float* q  = (const float*)d_in[0];
  const float* k  = (const float*)d_in[1];
  const float* qr = (const float*)d_in[2];
  const float* kr = (const float*)d_in[3];
  const float* v  = (const float*)d_in[4];
  float* out = (float*)d_out;
  la_attn<<<dim3(8, NBH), 512, SMEM_BYTES, stream>>>(q, k, qr, kr, v, out);
}